// Round 18
// baseline (335.142 us; speedup 1.0000x reference)
//
#include <hip/hip_runtime.h>
#include <hip/hip_fp16.h>

// ---------------------------------------------------------------------------
// GCN (3 layers) + global mean pool + linear, fp32 in/out, MI355X.
// t'[i] = dinv[i] * h[i] W^T; h_next[i] = relu(dinv[i]*(t'[i]+sum t'[j]) + b)
// R3-R5: scattered 4B global stores/atomics = ~32B HBM sector each. Dense only.
// R9: fp16 t (128B row = 1 L2 line), absmax 1.2e-4.
// R11: LDS float-atomic scatter = never.
// R13: agg+mm fused at per-NODE granularity = 119us (barrier killed wave
//   slip; W reloaded per node-wave).
// R14: 317us @ 10 launches (~13us/launch = 40% of runtime).
// R16/R17 (counter-verified): cooperative persistent kernel is dead: not
//   graph-capturable (timed path silently used fallback) and 840us anyway
//   (grid-capped occupancy + cross-XCD grid.sync cost).
// R18: fusion at MATCHING granularity: aggmm block = 32 nodes (barrier
//   amortized 8 nodes/wave, W once per block, h rows in LDS not global,
//   grid 1563 -> ~20 waves/CU); sortfill emits t1 (owns dinv via lofs).
//   7 launches, -51MB h traffic.
// ---------------------------------------------------------------------------

#define CAPB 3072
#define BINTILE 4096
#define AGGK 32

__global__ __launch_bounds__(256) void init_kernel(int* __restrict__ fctr) {
    int idx = blockIdx.x * blockDim.x + threadIdx.x;
    if (idx < 512) fctr[idx] = 0;
}

// Bucket edges into 512 fine dst-ranges (fixed capacity CAPB, base=g*CAPB).
// Per 4096-edge tile: dst+bucket cached in regs; sweep1 LDS histogram; one
// global reservation per bucket; sweep2 dense 8-rec (64B) appends.
__global__ __launch_bounds__(256) void bin512_kernel(const int* __restrict__ src,
                                                     const int* __restrict__ dst,
                                                     int* __restrict__ fctr,
                                                     int2* __restrict__ recs2,
                                                     int e, int n) {
    __shared__ int lcnt[512], gbase[512];
    int tid = threadIdx.x;
    int s0  = blockIdx.x * BINTILE;
    lcnt[tid] = 0;
    lcnt[tid + 256] = 0;
    __syncthreads();
    int dv[16], bk[16];
#pragma unroll
    for (int k = 0; k < 16; ++k) {
        int i = s0 + tid + k * 256;  // coalesced
        if (i < e) {
            dv[k] = dst[i];
            bk[k] = (int)((512LL * dv[k]) / n);
            atomicAdd(&lcnt[bk[k]], 1);
        } else {
            bk[k] = -1;
        }
    }
    __syncthreads();
#pragma unroll
    for (int j = 0; j < 2; ++j) {
        int b = tid + j * 256;
        gbase[b] = b * CAPB + atomicAdd(&fctr[b], lcnt[b]);
        lcnt[b]  = 0;  // reuse as placement counter
    }
    __syncthreads();
#pragma unroll
    for (int k = 0; k < 16; ++k) {
        if (bk[k] >= 0) {
            int i = s0 + tid + k * 256;
            int p = gbase[bk[k]] + atomicAdd(&lcnt[bk[k]], 1);
            if (p < (bk[k] + 1) * CAPB) recs2[p] = make_int2(src[i], dv[k]);
        }
    }
}

// One block per fine bucket: inline region base (reduce over fctr, L2-hot),
// LDS counting sort -> dense csr, produces rp/dinv, THEN computes this
// bucket's t1 = fp16(dinv * x W1^T) (x staged coalesced into LDS; dinv from
// lofs; W1 loaded once per block). Kills the separate mm1 launch.
__global__ __launch_bounds__(256) void sortfill_mm_kernel(
    const int2* __restrict__ recs2, const int* __restrict__ fctr,
    int* __restrict__ rp, float* __restrict__ dinv, int* __restrict__ csr,
    const float* __restrict__ x, const float* __restrict__ W1,
    __half* __restrict__ t1, int n) {
    __shared__ int hist[128];
    __shared__ int lofs[129];
    __shared__ int stage[CAPB];
    __shared__ int redbuf[256];
    __shared__ float xrow[98 * 64];  // 25KB
    int g   = blockIdx.x;
    int N0  = (int)(((long long)n * g + 511) / 512);
    int N1  = (int)(((long long)n * (g + 1) + 511) / 512);
    int nn  = N1 - N0;  // <= 98
    int tid = threadIdx.x;
    int lane = tid & 63;
    int wave = tid >> 6;

    int partial = 0;
    for (int j = tid; j < g; j += 256) partial += min(fctr[j], CAPB);
    redbuf[tid] = partial;
    if (tid < 128) hist[tid] = 0;
    __syncthreads();
    for (int s = 128; s > 0; s >>= 1) {
        if (tid < s) redbuf[tid] += redbuf[tid + s];
        __syncthreads();
    }
    int base = redbuf[0];
    const int2* my = recs2 + (size_t)g * CAPB;
    int total = min(fctr[g], CAPB);
    for (int i = tid; i < total; i += 256)
        atomicAdd(&hist[my[i].y - N0], 1);
    __syncthreads();
    if (tid == 0) {
        int acc = 0;
        for (int k = 0; k < nn; ++k) { lofs[k] = acc; acc += hist[k]; }
        lofs[nn] = acc;
    }
    __syncthreads();
    if (tid < 128) hist[tid] = 0;  // placement counters
    __syncthreads();
    for (int i = tid; i < total; i += 256) {
        int2 rec = my[i];
        int  li  = rec.y - N0;
        int  pos = lofs[li] + atomicAdd(&hist[li], 1);
        stage[pos] = rec.x;  // pos < total <= CAPB
    }
    __syncthreads();
    for (int j = tid; j < total; j += 256) csr[base + j] = stage[j];
    if (tid < nn) {
        rp[N0 + tid]   = base + lofs[tid];
        int deg        = lofs[tid + 1] - lofs[tid];
        dinv[N0 + tid] = rsqrtf((float)(deg + 1));
    }
    if (g == 511 && tid == 0) rp[n] = base + total;

    // ---- fused mm1 for this bucket's nodes ----
    for (int idx = tid; idx < nn * 16; idx += 256)
        ((float4*)xrow)[idx] = ((const float4*)(x + (size_t)N0 * 64))[idx];
    float4 wreg[16];
    const float4* W4 = (const float4*)(W1 + lane * 64);
#pragma unroll
    for (int q = 0; q < 16; ++q) wreg[q] = W4[q];
    __syncthreads();
    for (int li = wave; li < nn; li += 4) {
        float dv = rsqrtf((float)(lofs[li + 1] - lofs[li] + 1));
        const float4* row = (const float4*)(xrow + li * 64);
        float acc = 0.0f;
#pragma unroll
        for (int q = 0; q < 16; ++q) {
            float4 hv = row[q];  // wave-uniform -> LDS broadcast
            acc += hv.x * wreg[q].x + hv.y * wreg[q].y +
                   hv.z * wreg[q].z + hv.w * wreg[q].w;
        }
        t1[(size_t)(N0 + li) * 64 + lane] = __float2half(acc * dv);
    }
}

// Fused agg + next-layer mm at 32-node granularity. Block = 32 consecutive
// nodes, 4 waves x 8 nodes. Phase A: proven 4x16 gather per node, h row ->
// LDS (8KB, never global). ONE barrier. Phase B: W once per block, each wave
// emits fp16 t_next rows for its nodes. Grid 1563 -> ~20 waves/CU.
__global__ __launch_bounds__(256) void aggmm_kernel(const __half* __restrict__ t,
                                                    const int* __restrict__ rp,
                                                    const int* __restrict__ cs,
                                                    const float* __restrict__ dinv,
                                                    const float* __restrict__ bias,
                                                    const float* __restrict__ Wn,
                                                    __half* __restrict__ tout, int n) {
    __shared__ float hrow[AGGK * 64];  // 8KB
    int N0 = blockIdx.x * AGGK;
    if (N0 >= n) return;
    int nn   = min(AGGK, n - N0);
    int tid  = threadIdx.x;
    int lane = tid & 63;
    int wave = tid >> 6;
    int grp  = lane >> 4;
    int fo   = (lane & 15) << 2;

    for (int li = wave; li < nn; li += 4) {
        int i   = N0 + li;
        int beg = rp[i];
        int end = rp[i + 1];
        float4 a0 = make_float4(0.f, 0.f, 0.f, 0.f);
        float4 a1 = a0, a2 = a0, a3 = a0;
        int e = beg + grp;
        for (; e + 12 < end; e += 16) {
            int s0 = cs[e];
            int s1 = cs[e + 4];
            int s2 = cs[e + 8];
            int s3 = cs[e + 12];
            uint2 u0 = *(const uint2*)(t + (size_t)s0 * 64 + fo);
            uint2 u1 = *(const uint2*)(t + (size_t)s1 * 64 + fo);
            uint2 u2 = *(const uint2*)(t + (size_t)s2 * 64 + fo);
            uint2 u3 = *(const uint2*)(t + (size_t)s3 * 64 + fo);
            float2 f;
            f = __half22float2(*(const __half2*)&u0.x); a0.x += f.x; a0.y += f.y;
            f = __half22float2(*(const __half2*)&u0.y); a0.z += f.x; a0.w += f.y;
            f = __half22float2(*(const __half2*)&u1.x); a1.x += f.x; a1.y += f.y;
            f = __half22float2(*(const __half2*)&u1.y); a1.z += f.x; a1.w += f.y;
            f = __half22float2(*(const __half2*)&u2.x); a2.x += f.x; a2.y += f.y;
            f = __half22float2(*(const __half2*)&u2.y); a2.z += f.x; a2.w += f.y;
            f = __half22float2(*(const __half2*)&u3.x); a3.x += f.x; a3.y += f.y;
            f = __half22float2(*(const __half2*)&u3.y); a3.z += f.x; a3.w += f.y;
        }
        for (; e < end; e += 4) {
            int s = cs[e];
            uint2 u = *(const uint2*)(t + (size_t)s * 64 + fo);
            float2 f;
            f = __half22float2(*(const __half2*)&u.x); a1.x += f.x; a1.y += f.y;
            f = __half22float2(*(const __half2*)&u.y); a1.z += f.x; a1.w += f.y;
        }
        float4 acc;
        acc.x = (a0.x + a1.x) + (a2.x + a3.x);
        acc.y = (a0.y + a1.y) + (a2.y + a3.y);
        acc.z = (a0.z + a1.z) + (a2.z + a3.z);
        acc.w = (a0.w + a1.w) + (a2.w + a3.w);
        acc.x += __shfl_xor(acc.x, 16, 64);
        acc.y += __shfl_xor(acc.y, 16, 64);
        acc.z += __shfl_xor(acc.z, 16, 64);
        acc.w += __shfl_xor(acc.w, 16, 64);
        acc.x += __shfl_xor(acc.x, 32, 64);
        acc.y += __shfl_xor(acc.y, 32, 64);
        acc.z += __shfl_xor(acc.z, 32, 64);
        acc.w += __shfl_xor(acc.w, 32, 64);
        if (grp == 0) {
            uint2 su = *(const uint2*)(t + (size_t)i * 64 + fo);
            float2 s01 = __half22float2(*(const __half2*)&su.x);
            float2 s23 = __half22float2(*(const __half2*)&su.y);
            float4 bv = *(const float4*)(bias + fo);
            float  dv = dinv[i];
            hrow[li * 64 + fo + 0] = fmaxf(fmaf(dv, acc.x + s01.x, bv.x), 0.0f);
            hrow[li * 64 + fo + 1] = fmaxf(fmaf(dv, acc.y + s01.y, bv.y), 0.0f);
            hrow[li * 64 + fo + 2] = fmaxf(fmaf(dv, acc.z + s23.x, bv.z), 0.0f);
            hrow[li * 64 + fo + 3] = fmaxf(fmaf(dv, acc.w + s23.y, bv.w), 0.0f);
        }
    }
    __syncthreads();
    // Phase B: next-layer matmul from LDS h rows; W once per block.
    float4 wreg[16];
    const float4* W4 = (const float4*)(Wn + lane * 64);
#pragma unroll
    for (int q = 0; q < 16; ++q) wreg[q] = W4[q];
    for (int li = wave; li < nn; li += 4) {
        int i = N0 + li;
        const float4* row = (const float4*)(hrow + li * 64);
        float acc = 0.0f;
#pragma unroll
        for (int q = 0; q < 16; ++q) {
            float4 hv = row[q];  // wave-uniform -> LDS broadcast
            acc += hv.x * wreg[q].x + hv.y * wreg[q].y +
                   hv.z * wreg[q].z + hv.w * wreg[q].w;
        }
        tout[(size_t)i * 64 + lane] = __float2half(acc * dinv[i]);
    }
}

// Final-layer agg (writes fp32 h for pooling). R14-proven.
__global__ __launch_bounds__(256) void agg_kernel(const __half* __restrict__ t,
                                                  const int* __restrict__ rp,
                                                  const int* __restrict__ cs,
                                                  const float* __restrict__ dinv,
                                                  const float* __restrict__ bias,
                                                  float* __restrict__ hout, int n) {
    int gw   = (blockIdx.x * blockDim.x + threadIdx.x) >> 6;
    int lane = threadIdx.x & 63;
    if (gw >= n) return;
    int i   = gw;
    int grp = lane >> 4;
    int fo  = (lane & 15) << 2;
    int beg = rp[i];
    int end = rp[i + 1];

    float4 a0 = make_float4(0.f, 0.f, 0.f, 0.f);
    float4 a1 = a0, a2 = a0, a3 = a0;
    int e = beg + grp;
    for (; e + 12 < end; e += 16) {
        int s0 = cs[e];
        int s1 = cs[e + 4];
        int s2 = cs[e + 8];
        int s3 = cs[e + 12];
        uint2 u0 = *(const uint2*)(t + (size_t)s0 * 64 + fo);
        uint2 u1 = *(const uint2*)(t + (size_t)s1 * 64 + fo);
        uint2 u2 = *(const uint2*)(t + (size_t)s2 * 64 + fo);
        uint2 u3 = *(const uint2*)(t + (size_t)s3 * 64 + fo);
        float2 f;
        f = __half22float2(*(const __half2*)&u0.x); a0.x += f.x; a0.y += f.y;
        f = __half22float2(*(const __half2*)&u0.y); a0.z += f.x; a0.w += f.y;
        f = __half22float2(*(const __half2*)&u1.x); a1.x += f.x; a1.y += f.y;
        f = __half22float2(*(const __half2*)&u1.y); a1.z += f.x; a1.w += f.y;
        f = __half22float2(*(const __half2*)&u2.x); a2.x += f.x; a2.y += f.y;
        f = __half22float2(*(const __half2*)&u2.y); a2.z += f.x; a2.w += f.y;
        f = __half22float2(*(const __half2*)&u3.x); a3.x += f.x; a3.y += f.y;
        f = __half22float2(*(const __half2*)&u3.y); a3.z += f.x; a3.w += f.y;
    }
    for (; e < end; e += 4) {
        int s = cs[e];
        uint2 u = *(const uint2*)(t + (size_t)s * 64 + fo);
        float2 f;
        f = __half22float2(*(const __half2*)&u.x); a1.x += f.x; a1.y += f.y;
        f = __half22float2(*(const __half2*)&u.y); a1.z += f.x; a1.w += f.y;
    }
    float4 acc;
    acc.x = (a0.x + a1.x) + (a2.x + a3.x);
    acc.y = (a0.y + a1.y) + (a2.y + a3.y);
    acc.z = (a0.z + a1.z) + (a2.z + a3.z);
    acc.w = (a0.w + a1.w) + (a2.w + a3.w);
    acc.x += __shfl_xor(acc.x, 16, 64);
    acc.y += __shfl_xor(acc.y, 16, 64);
    acc.z += __shfl_xor(acc.z, 16, 64);
    acc.w += __shfl_xor(acc.w, 16, 64);
    acc.x += __shfl_xor(acc.x, 32, 64);
    acc.y += __shfl_xor(acc.y, 32, 64);
    acc.z += __shfl_xor(acc.z, 32, 64);
    acc.w += __shfl_xor(acc.w, 32, 64);
    if (grp == 0) {
        uint2 su = *(const uint2*)(t + (size_t)i * 64 + fo);
        float2 s01 = __half22float2(*(const __half2*)&su.x);
        float2 s23 = __half22float2(*(const __half2*)&su.y);
        float4 bv = *(const float4*)(bias + fo);
        float  dv = dinv[i];
        float4 o;
        o.x = fmaxf(fmaf(dv, acc.x + s01.x, bv.x), 0.0f);
        o.y = fmaxf(fmaf(dv, acc.y + s01.y, bv.y), 0.0f);
        o.z = fmaxf(fmaf(dv, acc.z + s23.x, bv.z), 0.0f);
        o.w = fmaxf(fmaf(dv, acc.w + s23.y, bv.w), 0.0f);
        *(float4*)(hout + (size_t)i * 64 + fo) = o;
    }
}

// Fused mean-pool + linear: block-per-graph, binary-search bounds,
// register accumulate, zero atomics. R14-proven.
__global__ __launch_bounds__(256) void poolfinal_kernel(const float* __restrict__ h,
                                                        const int* __restrict__ batch,
                                                        const float* __restrict__ Wl,
                                                        const float* __restrict__ bl,
                                                        float* __restrict__ out,
                                                        int n) {
    __shared__ float red[4][64];
    int b    = blockIdx.x;
    int tid  = threadIdx.x;
    int lane = tid & 63;
    int w    = tid >> 6;
    int l = 0, r = n;
    while (l < r) { int m = (l + r) >> 1; if (batch[m] < b) l = m + 1; else r = m; }
    int lo = l;
    r = n;
    while (l < r) { int m = (l + r) >> 1; if (batch[m] < b + 1) l = m + 1; else r = m; }
    int hi = l;
    float acc = 0.0f;
    for (int i = lo + w; i < hi; i += 4) acc += h[(size_t)i * 64 + lane];
    red[w][lane] = acc;
    __syncthreads();
    if (w == 0) {
        float s = (red[0][lane] + red[1][lane]) + (red[2][lane] + red[3][lane]);
        float c = (float)(hi - lo);
        red[0][lane] = s / fmaxf(c, 1.0f);
    }
    __syncthreads();
    if (tid < 16) {
        float a = bl[tid];
        const float* wr = Wl + tid * 64;
#pragma unroll
        for (int k = 0; k < 64; ++k) a += red[0][k] * wr[k];
        out[b * 16 + tid] = a;
    }
}

extern "C" void kernel_launch(void* const* d_in, const int* in_sizes, int n_in,
                              void* d_out, int out_size, void* d_ws, size_t ws_size,
                              hipStream_t stream) {
    const float* x    = (const float*)d_in[0];
    const int*   ei   = (const int*)d_in[1];
    const int*   batch= (const int*)d_in[2];
    const float* W1   = (const float*)d_in[3];
    const float* b1   = (const float*)d_in[4];
    const float* W2   = (const float*)d_in[5];
    const float* b2   = (const float*)d_in[6];
    const float* W3   = (const float*)d_in[7];
    const float* b3   = (const float*)d_in[8];
    const float* Wl   = (const float*)d_in[9];
    const float* bl   = (const float*)d_in[10];
    float* out = (float*)d_out;

    int n  = in_sizes[0] / 64;   // 50000 nodes
    int e  = in_sizes[1] / 2;    // 1250000 edges
    int nb = out_size / 16;      // 512 graphs

    const int* esrc = ei;
    const int* edst = ei + e;

    char* p = (char*)d_ws;
    auto carve = [&](size_t bytes) {
        char* r = p;
        p += (bytes + 255) & ~(size_t)255;
        return r;
    };
    size_t featBytes = (size_t)n * 64 * 4;     // 12.80 MB (fp32 h)
    size_t recsBytes = (size_t)512 * CAPB * 8; // 12.58 MB recs2
    size_t bufBBytes = recsBytes > featBytes ? recsBytes : featBytes;

    float*  dinv  = (float*)carve((size_t)n * 4);
    int*    rp    = (int*)  carve((size_t)(n + 1) * 4);
    int*    csr   = (int*)  carve((size_t)e * 4);
    __half* bufT  = (__half*)carve((size_t)n * 64 * 2);  // fp16 t ping (6.4 MB)
    __half* bufT2 = (__half*)carve((size_t)n * 64 * 2);  // fp16 t pong (6.4 MB)
    float*  bufB  = (float*)carve(bufBBytes);            // recs2, then final h
    int*    fctr  = (int*)  carve(512 * 4);
    int2*   recs2 = (int2*)bufB;  // dead before agg3 writes bufB

    dim3 blk(256);
    int gBIN = (e + BINTILE - 1) / BINTILE;  // 306 tiles
    int gAGG = (n + 3) / 4;                  // R14 agg: one node per wave
    int gAMM = (n + AGGK - 1) / AGGK;        // 1563 fused blocks

    init_kernel<<<2, blk, 0, stream>>>(fctr);
    bin512_kernel<<<gBIN, blk, 0, stream>>>(esrc, edst, fctr, recs2, e, n);
    sortfill_mm_kernel<<<512, blk, 0, stream>>>(recs2, fctr, rp, dinv, csr,
                                                x, W1, bufT, n);
    aggmm_kernel<<<gAMM, blk, 0, stream>>>(bufT, rp, csr, dinv, b1, W2, bufT2, n);
    aggmm_kernel<<<gAMM, blk, 0, stream>>>(bufT2, rp, csr, dinv, b2, W3, bufT, n);
    agg_kernel<<<gAGG, blk, 0, stream>>>(bufT, rp, csr, dinv, b3, bufB, n);
    poolfinal_kernel<<<nb, blk, 0, stream>>>(bufB, batch, Wl, bl, out, n);
}

// Round 19
// 308.210 us; speedup vs baseline: 1.0874x; 1.0874x over previous
//
#include <hip/hip_runtime.h>
#include <hip/hip_fp16.h>

// ---------------------------------------------------------------------------
// GCN (3 layers) + global mean pool + linear, fp32 in/out, MI355X.
// t'[i] = dinv[i] * h[i] W^T; h_next[i] = relu(dinv[i]*(t'[i]+sum t'[j]) + b)
// R3-R5: scattered 4B global stores/atomics = ~32B HBM sector each. Dense only.
// R9: fp16 t (128B row = 1 L2 line), absmax 1.2e-4.
// R11: LDS float-atomic scatter = never.
// R13/R18 (counter-verified): fusing agg with mm fails at ANY granularity
//   that cuts agg's wave count: R13 per-node (119us, W reload), R18 32-node
//   blocks (82us, occupancy 63%->30%, 8x fewer waves). The gather is pure
//   TLP-hidden; agg must keep one node per wave (50000 waves).
// R16/R17: cooperative persistent kernel dead (not capturable; 840us anyway).
// R14: 317us @ 10 launches (~13us/launch = 40% of runtime).
// R19: R14 structure + the ONE fusion that worked (R18 sortfill_mm: matched
//   512-block granularity, adds work to idle waves without cutting TLP).
//   9 launches.
// ---------------------------------------------------------------------------

#define CAPB 3072
#define BINTILE 4096

__global__ __launch_bounds__(256) void init_kernel(int* __restrict__ fctr) {
    int idx = blockIdx.x * blockDim.x + threadIdx.x;
    if (idx < 512) fctr[idx] = 0;
}

// Bucket edges into 512 fine dst-ranges (fixed capacity CAPB, base=g*CAPB).
// Per 4096-edge tile: dst+bucket cached in regs; sweep1 LDS histogram; one
// global reservation per bucket; sweep2 dense 8-rec (64B) appends.
__global__ __launch_bounds__(256) void bin512_kernel(const int* __restrict__ src,
                                                     const int* __restrict__ dst,
                                                     int* __restrict__ fctr,
                                                     int2* __restrict__ recs2,
                                                     int e, int n) {
    __shared__ int lcnt[512], gbase[512];
    int tid = threadIdx.x;
    int s0  = blockIdx.x * BINTILE;
    lcnt[tid] = 0;
    lcnt[tid + 256] = 0;
    __syncthreads();
    int dv[16], bk[16];
#pragma unroll
    for (int k = 0; k < 16; ++k) {
        int i = s0 + tid + k * 256;  // coalesced
        if (i < e) {
            dv[k] = dst[i];
            bk[k] = (int)((512LL * dv[k]) / n);
            atomicAdd(&lcnt[bk[k]], 1);
        } else {
            bk[k] = -1;
        }
    }
    __syncthreads();
#pragma unroll
    for (int j = 0; j < 2; ++j) {
        int b = tid + j * 256;
        gbase[b] = b * CAPB + atomicAdd(&fctr[b], lcnt[b]);
        lcnt[b]  = 0;  // reuse as placement counter
    }
    __syncthreads();
#pragma unroll
    for (int k = 0; k < 16; ++k) {
        if (bk[k] >= 0) {
            int i = s0 + tid + k * 256;
            int p = gbase[bk[k]] + atomicAdd(&lcnt[bk[k]], 1);
            if (p < (bk[k] + 1) * CAPB) recs2[p] = make_int2(src[i], dv[k]);
        }
    }
}

// One block per fine bucket: inline region base (reduce over fctr, L2-hot),
// LDS counting sort -> dense csr, produces rp/dinv, THEN computes this
// bucket's t1 = fp16(dinv * x W1^T) (x staged coalesced into LDS; dinv from
// lofs; W1 loaded once per block). Matched granularity: adds work to the
// existing 512 blocks without cutting any kernel's wave count.
__global__ __launch_bounds__(256) void sortfill_mm_kernel(
    const int2* __restrict__ recs2, const int* __restrict__ fctr,
    int* __restrict__ rp, float* __restrict__ dinv, int* __restrict__ csr,
    const float* __restrict__ x, const float* __restrict__ W1,
    __half* __restrict__ t1, int n) {
    __shared__ int hist[128];
    __shared__ int lofs[129];
    __shared__ int stage[CAPB];
    __shared__ int redbuf[256];
    __shared__ float xrow[98 * 64];  // 25KB
    int g   = blockIdx.x;
    int N0  = (int)(((long long)n * g + 511) / 512);
    int N1  = (int)(((long long)n * (g + 1) + 511) / 512);
    int nn  = N1 - N0;  // <= 98
    int tid = threadIdx.x;
    int lane = tid & 63;
    int wave = tid >> 6;

    int partial = 0;
    for (int j = tid; j < g; j += 256) partial += min(fctr[j], CAPB);
    redbuf[tid] = partial;
    if (tid < 128) hist[tid] = 0;
    __syncthreads();
    for (int s = 128; s > 0; s >>= 1) {
        if (tid < s) redbuf[tid] += redbuf[tid + s];
        __syncthreads();
    }
    int base = redbuf[0];
    const int2* my = recs2 + (size_t)g * CAPB;
    int total = min(fctr[g], CAPB);
    for (int i = tid; i < total; i += 256)
        atomicAdd(&hist[my[i].y - N0], 1);
    __syncthreads();
    if (tid == 0) {
        int acc = 0;
        for (int k = 0; k < nn; ++k) { lofs[k] = acc; acc += hist[k]; }
        lofs[nn] = acc;
    }
    __syncthreads();
    if (tid < 128) hist[tid] = 0;  // placement counters
    __syncthreads();
    for (int i = tid; i < total; i += 256) {
        int2 rec = my[i];
        int  li  = rec.y - N0;
        int  pos = lofs[li] + atomicAdd(&hist[li], 1);
        stage[pos] = rec.x;  // pos < total <= CAPB
    }
    __syncthreads();
    for (int j = tid; j < total; j += 256) csr[base + j] = stage[j];
    if (tid < nn) {
        rp[N0 + tid]   = base + lofs[tid];
        int deg        = lofs[tid + 1] - lofs[tid];
        dinv[N0 + tid] = rsqrtf((float)(deg + 1));
    }
    if (g == 511 && tid == 0) rp[n] = base + total;

    // ---- fused mm1 for this bucket's nodes ----
    for (int idx = tid; idx < nn * 16; idx += 256)
        ((float4*)xrow)[idx] = ((const float4*)(x + (size_t)N0 * 64))[idx];
    float4 wreg[16];
    const float4* W4 = (const float4*)(W1 + lane * 64);
#pragma unroll
    for (int q = 0; q < 16; ++q) wreg[q] = W4[q];
    __syncthreads();
    for (int li = wave; li < nn; li += 4) {
        float dv = rsqrtf((float)(lofs[li + 1] - lofs[li] + 1));
        const float4* row = (const float4*)(xrow + li * 64);
        float acc = 0.0f;
#pragma unroll
        for (int q = 0; q < 16; ++q) {
            float4 hv = row[q];  // wave-uniform -> LDS broadcast
            acc += hv.x * wreg[q].x + hv.y * wreg[q].y +
                   hv.z * wreg[q].z + hv.w * wreg[q].w;
        }
        t1[(size_t)(N0 + li) * 64 + lane] = __float2half(acc * dv);
    }
}

// t[i][o] = fp16( dinv[i] * sum_k h[i][k] * W[o][k] )  (layers 2,3)
// 256 thr = 4 waves; 64 nodes/block. W row per lane in 16 float4 regs;
// 64 h-rows staged in LDS, read as broadcast float4. Row store = dense 128B.
__global__ __launch_bounds__(256) void mm_kernel(const float* __restrict__ h,
                                                 const float* __restrict__ W,
                                                 const float* __restrict__ dinv,
                                                 __half* __restrict__ t, int n) {
    __shared__ float hs[64 * 64];
    int tid  = threadIdx.x;
    int lane = tid & 63;
    int wave = tid >> 6;
    int base = blockIdx.x * 64;

    float4 wreg[16];
    const float4* W4 = (const float4*)(W + lane * 64);
#pragma unroll
    for (int q = 0; q < 16; ++q) wreg[q] = W4[q];

    int nrows = min(64, n - base);
    const float4* h4  = (const float4*)(h + (size_t)base * 64);
    float4*       hs4 = (float4*)hs;
    for (int idx = tid; idx < nrows * 16; idx += 256) hs4[idx] = h4[idx];
    __syncthreads();

    for (int r = wave * 16; r < wave * 16 + 16; ++r) {
        int i = base + r;
        if (i >= n) break;
        const float4* row = (const float4*)(hs + r * 64);
        float acc = 0.0f;
#pragma unroll
        for (int q = 0; q < 16; ++q) {
            float4 hv = row[q];  // wave-uniform address -> LDS broadcast
            acc += hv.x * wreg[q].x + hv.y * wreg[q].y +
                   hv.z * wreg[q].z + hv.w * wreg[q].w;
        }
        t[(size_t)i * 64 + lane] = __float2half(acc * dinv[i]);
    }
}

// One wave per node (50000 waves -- agg is pure TLP-hidden, never reduce
// wave count): 4 edge-groups x 16 feature-lanes, half4 gathers (4 rows per
// vmem instr, 128B rows), 4-deep unroll, shfl_xor(16,32) reduce, grp0
// dense 256B store.
__global__ __launch_bounds__(256) void agg_kernel(const __half* __restrict__ t,
                                                  const int* __restrict__ rp,
                                                  const int* __restrict__ cs,
                                                  const float* __restrict__ dinv,
                                                  const float* __restrict__ bias,
                                                  float* __restrict__ hout, int n) {
    int gw   = (blockIdx.x * blockDim.x + threadIdx.x) >> 6;
    int lane = threadIdx.x & 63;
    if (gw >= n) return;
    int i   = gw;
    int grp = lane >> 4;
    int fo  = (lane & 15) << 2;
    int beg = rp[i];
    int end = rp[i + 1];

    float4 a0 = make_float4(0.f, 0.f, 0.f, 0.f);
    float4 a1 = a0, a2 = a0, a3 = a0;
    int e = beg + grp;
    for (; e + 12 < end; e += 16) {
        int s0 = cs[e];
        int s1 = cs[e + 4];
        int s2 = cs[e + 8];
        int s3 = cs[e + 12];
        uint2 u0 = *(const uint2*)(t + (size_t)s0 * 64 + fo);
        uint2 u1 = *(const uint2*)(t + (size_t)s1 * 64 + fo);
        uint2 u2 = *(const uint2*)(t + (size_t)s2 * 64 + fo);
        uint2 u3 = *(const uint2*)(t + (size_t)s3 * 64 + fo);
        float2 f;
        f = __half22float2(*(const __half2*)&u0.x); a0.x += f.x; a0.y += f.y;
        f = __half22float2(*(const __half2*)&u0.y); a0.z += f.x; a0.w += f.y;
        f = __half22float2(*(const __half2*)&u1.x); a1.x += f.x; a1.y += f.y;
        f = __half22float2(*(const __half2*)&u1.y); a1.z += f.x; a1.w += f.y;
        f = __half22float2(*(const __half2*)&u2.x); a2.x += f.x; a2.y += f.y;
        f = __half22float2(*(const __half2*)&u2.y); a2.z += f.x; a2.w += f.y;
        f = __half22float2(*(const __half2*)&u3.x); a3.x += f.x; a3.y += f.y;
        f = __half22float2(*(const __half2*)&u3.y); a3.z += f.x; a3.w += f.y;
    }
    for (; e < end; e += 4) {
        int s = cs[e];
        uint2 u = *(const uint2*)(t + (size_t)s * 64 + fo);
        float2 f;
        f = __half22float2(*(const __half2*)&u.x); a1.x += f.x; a1.y += f.y;
        f = __half22float2(*(const __half2*)&u.y); a1.z += f.x; a1.w += f.y;
    }
    float4 acc;
    acc.x = (a0.x + a1.x) + (a2.x + a3.x);
    acc.y = (a0.y + a1.y) + (a2.y + a3.y);
    acc.z = (a0.z + a1.z) + (a2.z + a3.z);
    acc.w = (a0.w + a1.w) + (a2.w + a3.w);
    acc.x += __shfl_xor(acc.x, 16, 64);
    acc.y += __shfl_xor(acc.y, 16, 64);
    acc.z += __shfl_xor(acc.z, 16, 64);
    acc.w += __shfl_xor(acc.w, 16, 64);
    acc.x += __shfl_xor(acc.x, 32, 64);
    acc.y += __shfl_xor(acc.y, 32, 64);
    acc.z += __shfl_xor(acc.z, 32, 64);
    acc.w += __shfl_xor(acc.w, 32, 64);
    if (grp == 0) {
        uint2 su = *(const uint2*)(t + (size_t)i * 64 + fo);
        float2 s01 = __half22float2(*(const __half2*)&su.x);
        float2 s23 = __half22float2(*(const __half2*)&su.y);
        float4 bv = *(const float4*)(bias + fo);
        float  dv = dinv[i];
        float4 o;
        o.x = fmaxf(fmaf(dv, acc.x + s01.x, bv.x), 0.0f);
        o.y = fmaxf(fmaf(dv, acc.y + s01.y, bv.y), 0.0f);
        o.z = fmaxf(fmaf(dv, acc.z + s23.x, bv.z), 0.0f);
        o.w = fmaxf(fmaf(dv, acc.w + s23.y, bv.w), 0.0f);
        *(float4*)(hout + (size_t)i * 64 + fo) = o;
    }
}

// Fused mean-pool + linear: block-per-graph, binary-search bounds,
// register accumulate, zero atomics.
__global__ __launch_bounds__(256) void poolfinal_kernel(const float* __restrict__ h,
                                                        const int* __restrict__ batch,
                                                        const float* __restrict__ Wl,
                                                        const float* __restrict__ bl,
                                                        float* __restrict__ out,
                                                        int n) {
    __shared__ float red[4][64];
    int b    = blockIdx.x;
    int tid  = threadIdx.x;
    int lane = tid & 63;
    int w    = tid >> 6;
    int l = 0, r = n;
    while (l < r) { int m = (l + r) >> 1; if (batch[m] < b) l = m + 1; else r = m; }
    int lo = l;
    r = n;
    while (l < r) { int m = (l + r) >> 1; if (batch[m] < b + 1) l = m + 1; else r = m; }
    int hi = l;
    float acc = 0.0f;
    for (int i = lo + w; i < hi; i += 4) acc += h[(size_t)i * 64 + lane];
    red[w][lane] = acc;
    __syncthreads();
    if (w == 0) {
        float s = (red[0][lane] + red[1][lane]) + (red[2][lane] + red[3][lane]);
        float c = (float)(hi - lo);
        red[0][lane] = s / fmaxf(c, 1.0f);
    }
    __syncthreads();
    if (tid < 16) {
        float a = bl[tid];
        const float* wr = Wl + tid * 64;
#pragma unroll
        for (int k = 0; k < 64; ++k) a += red[0][k] * wr[k];
        out[b * 16 + tid] = a;
    }
}

extern "C" void kernel_launch(void* const* d_in, const int* in_sizes, int n_in,
                              void* d_out, int out_size, void* d_ws, size_t ws_size,
                              hipStream_t stream) {
    const float* x    = (const float*)d_in[0];
    const int*   ei   = (const int*)d_in[1];
    const int*   batch= (const int*)d_in[2];
    const float* W1   = (const float*)d_in[3];
    const float* b1   = (const float*)d_in[4];
    const float* W2   = (const float*)d_in[5];
    const float* b2   = (const float*)d_in[6];
    const float* W3   = (const float*)d_in[7];
    const float* b3   = (const float*)d_in[8];
    const float* Wl   = (const float*)d_in[9];
    const float* bl   = (const float*)d_in[10];
    float* out = (float*)d_out;

    int n  = in_sizes[0] / 64;   // 50000 nodes
    int e  = in_sizes[1] / 2;    // 1250000 edges
    int nb = out_size / 16;      // 512 graphs

    const int* esrc = ei;
    const int* edst = ei + e;

    char* p = (char*)d_ws;
    auto carve = [&](size_t bytes) {
        char* r = p;
        p += (bytes + 255) & ~(size_t)255;
        return r;
    };
    size_t featBytes = (size_t)n * 64 * 4;     // 12.80 MB (fp32 h)
    size_t recsBytes = (size_t)512 * CAPB * 8; // 12.58 MB recs2
    size_t bufBBytes = recsBytes > featBytes ? recsBytes : featBytes;

    float*  dinv = (float*)carve((size_t)n * 4);
    int*    rp   = (int*)  carve((size_t)(n + 1) * 4);
    int*    csr  = (int*)  carve((size_t)e * 4);
    __half* bufT = (__half*)carve((size_t)n * 64 * 2);  // fp16 t (6.4 MB)
    float*  bufB = (float*)carve(bufBBytes);            // recs2, then h
    int*    fctr = (int*)  carve(512 * 4);
    int2*   recs2 = (int2*)bufB;  // dead before agg1 writes bufB

    dim3 blk(256);
    int gBIN = (e + BINTILE - 1) / BINTILE;  // 306 tiles
    int gMM  = (n + 63) / 64;
    int gAGG = (n + 3) / 4;  // one node per wave

    init_kernel<<<2, blk, 0, stream>>>(fctr);
    bin512_kernel<<<gBIN, blk, 0, stream>>>(esrc, edst, fctr, recs2, e, n);
    sortfill_mm_kernel<<<512, blk, 0, stream>>>(recs2, fctr, rp, dinv, csr,
                                                x, W1, bufT, n);
    agg_kernel<<<gAGG, blk, 0, stream>>>(bufT, rp, csr, dinv, b1, bufB, n);
    mm_kernel<<<gMM, blk, 0, stream>>>(bufB, W2, dinv, bufT, n);
    agg_kernel<<<gAGG, blk, 0, stream>>>(bufT, rp, csr, dinv, b2, bufB, n);
    mm_kernel<<<gMM, blk, 0, stream>>>(bufB, W3, dinv, bufT, n);
    agg_kernel<<<gAGG, blk, 0, stream>>>(bufT, rp, csr, dinv, b3, bufB, n);
    poolfinal_kernel<<<nb, blk, 0, stream>>>(bufB, batch, Wl, bl, out, n);
}